// Round 8
// baseline (188.640 us; speedup 1.0000x reference)
//
#include <hip/hip_runtime.h>
#include <hip/hip_bf16.h>
#include <math.h>

#define N_TOK 65536
#define DIM   256
#define NEXP  8

using frag_ab = __attribute__((ext_vector_type(8))) short;   // 8 bf16 (4 VGPRs)
using frag_cd = __attribute__((ext_vector_type(4))) float;   // 4 fp32 acc

__device__ __forceinline__ unsigned short f2bf(float f) {
  unsigned u = __float_as_uint(f);
  u += 0x7FFFu + ((u >> 16) & 1u);   // RNE
  return (unsigned short)(u >> 16);
}

// async 16B global->LDS: lds base is wave-uniform; lane i lands at base+i*16
__device__ __forceinline__ void gl2lds16(const unsigned short* g, unsigned short* l) {
  __builtin_amdgcn_global_load_lds(
      (const __attribute__((address_space(1))) void*)g,
      (__attribute__((address_space(3))) void*)l, 16, 0, 0);
}

// meta int layout in ws: [0:64)=pair counts, [64:128)=pair base, [128:192)=cursor

// ---- k_prep: one wave per (e,o) row. Reads w ONCE: converts to bf16
// fragment-major Wb [e][k>>3][col][8] AND computes c[e][o]=bias_e.W_e[o].
__global__ __launch_bounds__(256) void k_prep(
    const float* __restrict__ w,      // expert_weight [E][OUT][D]
    const float* __restrict__ bias,   // expert_bias   [E][D]
    unsigned short* __restrict__ Wb,
    float* __restrict__ c,            // [E][OUT]
    int* __restrict__ meta) {
  int tid = threadIdx.x;
  int wid = (blockIdx.x * 256 + tid) >> 6;    // 0..2047 : one wave per (e,o)
  int lane = tid & 63;
  int e = wid >> 8, o = wid & 255;
  const float* wr = w + (size_t)(e * 256 + o) * DIM + lane * 4;
  float4 wv = *(const float4*)wr;             // row read once, coalesced
  const float* br = bias + e * DIM + lane * 4;
  float4 bv = *(const float4*)br;             // 8 KB total, L2-hot
  float s = wv.x * bv.x + wv.y * bv.y + wv.z * bv.z + wv.w * bv.w;
  #pragma unroll
  for (int m = 1; m < 64; m <<= 1) s += __shfl_xor(s, m, 64);
  if (lane == 0) c[e * 256 + o] = s;
  // fragment-major store: d = lane*4 -> elem e*65536 + (d>>3)*2048 + o*8 + (d&7)
  ushort4 h; h.x = f2bf(wv.x); h.y = f2bf(wv.y); h.z = f2bf(wv.z); h.w = f2bf(wv.w);
  *(ushort4*)(Wb + (size_t)e * 65536 + (size_t)(lane >> 1) * 2048 + o * 8 + (lane & 1) * 4) = h;
  if (blockIdx.x == 0 && tid < 192) meta[tid] = 0;
}

// ---- k_gating v2: 64 tok/block (1024 blocks -> 4 blocks/CU), 256 threads =
// 4 threads/token (dims cc === sub mod 4). Register double-buffer: chunk dc+1
// loaded to regs before computing dc (overlap). Reduce: 4-lane f64 butterfly
// (no sPar LDS, no extra barrier).
__global__ __launch_bounds__(256) void k_gating(
    const float* __restrict__ x,      // [N][D]
    const float* __restrict__ wg,     // [D][E]
    unsigned short* __restrict__ xb,  // [N][D] bf16
    int* __restrict__ routeE,         // [N] packed e1 | e2<<8
    float* __restrict__ routeG,       // [N][2]
    int* __restrict__ meta) {
  __shared__ double swg[DIM * NEXP];    // 16 KB
  __shared__ float  chunk[64 * 35];     // 8.96 KB (pad 35: bank=3*tk+cc, <=3-way)
  __shared__ int    hcnt[64];
  int tid = threadIdx.x;
  int tok0 = blockIdx.x * 64;
  int tk = tid >> 2, sub = tid & 3;     // token-local id, dim-quarter

  for (int i = tid; i < DIM * NEXP; i += 256) swg[i] = (double)wg[i];
  if (tid < 64) hcnt[tid] = 0;

  double p[NEXP];
  #pragma unroll
  for (int e = 0; e < NEXP; e++) p[e] = 0.0;

  // staging map: f in [0,512) covers [64 tok][32 dim] as float4s
  int f0 = tid, f1 = 256 + tid;
  int r0 = f0 >> 3, c40 = (f0 & 7) * 4;
  int r1 = f1 >> 3, c41 = (f1 & 7) * 4;
  const float* xs0 = x + (size_t)(tok0 + r0) * DIM + c40;
  const float* xs1 = x + (size_t)(tok0 + r1) * DIM + c41;
  unsigned short* xd0 = xb + (size_t)(tok0 + r0) * DIM + c40;
  unsigned short* xd1 = xb + (size_t)(tok0 + r1) * DIM + c41;

  float4 v0 = *(const float4*)(xs0);    // chunk 0 pre-loaded
  float4 v1 = *(const float4*)(xs1);

  for (int dc = 0; dc < 8; dc++) {      // 8 chunks of 32 dims
    __syncthreads();                    // prev compute done -> chunk reusable
    // store staged regs: LDS chunk + bf16 global
    {
      ushort4 h0; h0.x = f2bf(v0.x); h0.y = f2bf(v0.y); h0.z = f2bf(v0.z); h0.w = f2bf(v0.w);
      ushort4 h1; h1.x = f2bf(v1.x); h1.y = f2bf(v1.y); h1.z = f2bf(v1.z); h1.w = f2bf(v1.w);
      *(ushort4*)(xd0 + dc * 32) = h0;
      *(ushort4*)(xd1 + dc * 32) = h1;
      float* d0 = &chunk[r0 * 35 + c40];
      d0[0] = v0.x; d0[1] = v0.y; d0[2] = v0.z; d0[3] = v0.w;
      float* d1 = &chunk[r1 * 35 + c41];
      d1[0] = v1.x; d1[1] = v1.y; d1[2] = v1.z; d1[3] = v1.w;
    }
    // issue next chunk's loads BEFORE compute (overlap with this compute)
    float4 n0 = make_float4(0.f, 0.f, 0.f, 0.f);
    float4 n1 = make_float4(0.f, 0.f, 0.f, 0.f);
    if (dc < 7) {
      n0 = *(const float4*)(xs0 + (dc + 1) * 32);
      n1 = *(const float4*)(xs1 + (dc + 1) * 32);
    }
    __syncthreads();                    // chunk visible
    #pragma unroll
    for (int c8 = 0; c8 < 8; c8++) {    // this thread's 8 dims of the chunk
      int cc = c8 * 4 + sub;
      double xv = (double)chunk[tk * 35 + cc];
      const double* wrow = &swg[(dc * 32 + cc) * NEXP];  // 4 addrs, broadcast
      #pragma unroll
      for (int e = 0; e < NEXP; e++) p[e] += xv * wrow[e];
    }
    v0 = n0; v1 = n1;
  }

  // 4-lane butterfly reduce over the dim quarters (deterministic order)
  #pragma unroll
  for (int e = 0; e < NEXP; e++) {
    p[e] += __shfl_xor(p[e], 1, 64);
    p[e] += __shfl_xor(p[e], 2, 64);
  }

  if (sub == 0) {
    // top-2 (ties -> lowest index, matches jax.lax.top_k)
    int i1 = 0; double v1d = p[0];
    #pragma unroll
    for (int e = 1; e < NEXP; e++) { if (p[e] > v1d) { v1d = p[e]; i1 = e; } }
    int i2 = -1; double v2d = -1e300;
    #pragma unroll
    for (int e = 0; e < NEXP; e++) { if (e != i1 && p[e] > v2d) { v2d = p[e]; i2 = e; } }
    double t = exp(v2d - v1d);
    float g1 = (float)(1.0 / (1.0 + t));
    float g2 = 1.0f - g1;

    int n = tok0 + tk;
    routeE[n] = i1 | (i2 << 8);
    *(float2*)(routeG + 2 * (size_t)n) = make_float2(g1, g2);
    int a = i1 < i2 ? i1 : i2, b = i1 < i2 ? i2 : i1;
    atomicAdd(&hcnt[a * 8 + b], 1);
  }
  __syncthreads();
  if (tid < 64) atomicAdd(&meta[tid], hcnt[tid]);
}

// ---- k_scan: 64-aligned exclusive scan over 64 pair counts -----------------
__global__ void k_scan(int* __restrict__ meta) {
  if (threadIdx.x == 0) {
    int run = 0;
    for (int p = 0; p < 64; p++) {
      meta[64 + p] = run; meta[128 + p] = run;         // base, cursor
      run += ((meta[p] + 63) >> 6) << 6;
    }
  }
}

// ---- k_scatter: pair-grouped permutation; both gates per token --------------
__global__ __launch_bounds__(1024) void k_scatter(
    const int* __restrict__ routeE, const float* __restrict__ routeG,
    int* __restrict__ meta,
    int* __restrict__ srcTok, float* __restrict__ srcGA, float* __restrict__ srcGB) {
  __shared__ int cnt[64], bse[64];
  int tid = threadIdx.x;
  if (tid < 64) cnt[tid] = 0;
  __syncthreads();
  int n = blockIdx.x * 1024 + tid;
  int ep = routeE[n];
  int e1 = ep & 255, e2 = ep >> 8;
  float2 g = *(const float2*)(routeG + 2 * (size_t)n);
  int a = e1 < e2 ? e1 : e2, b = e1 < e2 ? e2 : e1;
  float ga = e1 < e2 ? g.x : g.y;      // gate of expert a (=min)
  float gb = e1 < e2 ? g.y : g.x;      // gate of expert b (=max)
  int pid = a * 8 + b;
  int r = atomicAdd(&cnt[pid], 1);
  __syncthreads();
  if (tid < 64) bse[tid] = atomicAdd(&meta[128 + tid], cnt[tid]);
  __syncthreads();
  int p = bse[pid] + r;
  srcTok[p] = n; srcGA[p] = ga; srcGB[p] = gb;
}

// ---- k_gemm_pair: pair-grouped fused GEMM. BM=64 tok, BN=256 (full OUT),
// 512 thr / 8 waves (2m x 4n), per-wave 32x64, acc[2][4].
// 16 clusters (8 per expert); B-frags stream from L2 (fragment-major) through
// a 3-DEEP STATIC NAMED register rotation bvA/bvB/bvC (rule-#20-safe: every
// buffer reference is a compile-time name; round-7's pointer-swap forced the
// buffers to scratch -> +14.5MB WRITE_SIZE, VGPR squeezed to 64, MfmaUtil
// DOWN). Cluster C computes from its buffer then refills it with C+3 ->
// ~2-cluster prefetch distance covers L2 latency; compiler derives counted
// vmcnt automatically. A-tile (64x256, 32 KB) staged once via gl2lds with
// proven XOR swizzle; zero barriers after the single staging drain.
// out written ONCE: v = sGB*acc - (sGA*cA[col] + sGB*cB[col]).
__global__ __launch_bounds__(512, 4) void k_gemm_pair(
    const unsigned short* __restrict__ xb,
    const unsigned short* __restrict__ Wb,   // fragment-major, see k_prep
    const int* __restrict__ meta,            // counts@0, base@64
    const int* __restrict__ srcTok,
    const float* __restrict__ srcGA, const float* __restrict__ srcGB,
    const float* __restrict__ c,
    float* __restrict__ out) {
  __shared__ unsigned short sA[4][64 * 64];    // 32 KB: all 4 K-subtiles
  __shared__ int   sTok[64];
  __shared__ float sGAs[64], sGBs[64];
  __shared__ float sCorA[256], sCorB[256];
  int tid = threadIdx.x;

  // map block -> (pair, m-tile)
  int rem = blockIdx.x, pid = 0, ne = 0;
  for (pid = 0; pid < 64; pid++) {
    ne = meta[pid];
    int tiles = (ne + 63) >> 6;
    if (rem < tiles) break;
    rem -= tiles;
  }
  if (pid == 64) return;
  int ea = pid >> 3, eb = pid & 7;
  int mt = rem;
  int slot0 = meta[64 + pid] + mt * 64;

  if (tid < 64) {
    int idx = mt * 64 + tid;
    bool v = idx < ne;
    sTok[tid]  = v ? srcTok[slot0 + tid] : 0;
    sGAs[tid]  = v ? srcGA[slot0 + tid] : 0.f;
    sGBs[tid]  = v ? srcGB[slot0 + tid] : 1.f;   // pad: ratio 0, never stored
  } else if (tid >= 128 && tid < 192) {
    ((float4*)sCorA)[tid - 128] = ((const float4*)(c + ea * 256))[tid - 128];
  } else if (tid >= 192 && tid < 256) {
    ((float4*)sCorB)[tid - 192] = ((const float4*)(c + eb * 256))[tid - 192];
  }
  __syncthreads();                       // sTok ready for staging addresses

  int w = tid >> 6, lane = tid & 63;
  int lrow = lane >> 3, lchk = lane & 7;

  // A staging: wave w -> rows [w*8, w*8+8), one 8-row group, 4 subtiles
  {
    int r = w * 8 + lrow;
    int cc = (lchk - r) & 7;             // global chunk for this lane's slot
    const unsigned short* src = xb + (size_t)sTok[r] * 256 + cc * 8;
    #pragma unroll
    for (int kk = 0; kk < 4; kk++)
      gl2lds16(src + kk * 64, &sA[kk][w * 8 * 64]);
  }
  __syncthreads();   // full drain once; sA read-only hereafter -> NO barriers

  // A fragment read offsets: row ra, k-chunk kc=ks*4+lk -> slot (kc+ra)&7
  int wm = w & 1, wn = w >> 1;           // 2 (m) x 4 (n) waves
  int lr = lane & 15, lk = lane >> 4;
  int offA[2][2];
  #pragma unroll
  for (int ks = 0; ks < 2; ks++)
    #pragma unroll
    for (int i = 0; i < 2; i++) {
      int ra = wm * 32 + i * 16 + lr;
      offA[ks][i] = ra * 64 + ((ks * 4 + lk + ra) & 7) * 8;
    }

  // B fragment bases (fragment-major): elem(e,col,k) at e*65536+(k>>3)*2048+col*8+(k&7)
  const unsigned short* bBaseA =
      Wb + (size_t)ea * 65536 + (size_t)lk * 2048 + (wn * 64 + lr) * 8;
  const unsigned short* bBaseB =
      Wb + (size_t)eb * 65536 + (size_t)lk * 2048 + (wn * 64 + lr) * 8;

  frag_cd acc[2][4];
  #pragma unroll
  for (int i = 0; i < 2; i++)
    #pragma unroll
    for (int j = 0; j < 4; j++)
      acc[i][j] = (frag_cd){0.f, 0.f, 0.f, 0.f};

  // cluster C in [0,16): expert = C<8 ? A : B, kk=(C&7)>>1, ks=C&1.
#define BPTR(C) (((C) < 8 ? bBaseA : bBaseB) + (((C) & 7) >> 1) * 16384 + ((C) & 1) * 8192)
#define LOADB(DST, C) do {                                                  \
    _Pragma("unroll")                                                       \
    for (int j = 0; j < 4; j++) DST[j] = *(const frag_ab*)(BPTR(C) + j * 128); \
  } while (0)

  // compute cluster C from named BUF, then refill BUF with cluster C+3.
#define CLUSTER(C, BUF) do {                                                \
    const int ks_ = (C) & 1, kk_ = ((C) & 7) >> 1;                          \
    frag_ab av0 = *(const frag_ab*)(&sA[kk_][0] + offA[ks_][0]);            \
    frag_ab av1 = *(const frag_ab*)(&sA[kk_][0] + offA[ks_][1]);            \
    _Pragma("unroll")                                                       \
    for (int j = 0; j < 4; j++) {                                           \
      acc[0][j] = __builtin_amdgcn_mfma_f32_16x16x32_bf16(av0, BUF[j], acc[0][j], 0, 0, 0); \
      acc[1][j] = __builtin_amdgcn_mfma_f32_16x16x32_bf16(av1, BUF[j], acc[1][j], 0, 0, 0); \
    }                                                                       \
    if ((C) + 3 < 16) LOADB(BUF, (C) + 3);                                  \
  } while (0)

  frag_ab bvA[4], bvB[4], bvC[4];
  LOADB(bvA, 0); LOADB(bvB, 1); LOADB(bvC, 2);

  CLUSTER(0, bvA);  CLUSTER(1, bvB);  CLUSTER(2, bvC);
  CLUSTER(3, bvA);  CLUSTER(4, bvB);  CLUSTER(5, bvC);
  CLUSTER(6, bvA);  CLUSTER(7, bvB);

  // between experts: acc *= sGA[m]/sGB[m] (per row); bv regs untouched
  #pragma unroll
  for (int i = 0; i < 2; i++)
    #pragma unroll
    for (int rr = 0; rr < 4; rr++) {
      int m = wm * 32 + i * 16 + lk * 4 + rr;
      float ratio = sGAs[m] / sGBs[m];
      #pragma unroll
      for (int j = 0; j < 4; j++) acc[i][j][rr] *= ratio;
    }

  CLUSTER(8, bvC);  CLUSTER(9, bvA);  CLUSTER(10, bvB); CLUSTER(11, bvC);
  CLUSTER(12, bvA); CLUSTER(13, bvB); CLUSTER(14, bvC); CLUSTER(15, bvA);

#undef CLUSTER
#undef LOADB
#undef BPTR

  // epilogue: C/D layout col=lane&15, row=(lane>>4)*4+reg  [m89-verified]
  // v = sGB*acc - (sGA*cA[col] + sGB*cB[col]); single write, no RMW.
  #pragma unroll
  for (int i = 0; i < 2; i++) {
    #pragma unroll
    for (int rr = 0; rr < 4; rr++) {
      int m = wm * 32 + i * 16 + lk * 4 + rr;
      if (mt * 64 + m < ne) {              // pad rows: no store
        int tokn = sTok[m];
        float sa = sGAs[m], sb = sGBs[m];
        float* orow = out + (size_t)tokn * 256;
        #pragma unroll
        for (int j = 0; j < 4; j++) {
          int col = wn * 64 + j * 16 + lr;
          orow[col] = sb * acc[i][j][rr] - (sa * sCorA[col] + sb * sCorB[col]);
        }
      }
    }
  }
}

extern "C" void kernel_launch(void* const* d_in, const int* in_sizes, int n_in,
                              void* d_out, int out_size, void* d_ws, size_t ws_size,
                              hipStream_t stream) {
  const float* x    = (const float*)d_in[0];  // [N][D]
  const float* wg   = (const float*)d_in[1];  // [D][E]
  const float* bias = (const float*)d_in[2];  // [E][D]
  const float* w    = (const float*)d_in[3];  // [E][OUT][D]
  float* out = (float*)d_out;
  char* ws = (char*)d_ws;

  // total ws usage: ~36.2 MB (proven >=39.6 MB available)
  unsigned short* xb = (unsigned short*)(ws);                 // 33,554,432 B
  unsigned short* Wb = (unsigned short*)(ws + 33554432);      //  1,048,576 B
  float* c           = (float*)(ws + 34603008);               //      8,192 B
  int* meta          = (int*)(ws + 34611200);                 //      1,024 B (192 ints used)
  int* routeE        = (int*)(ws + 34612224);                 //    262,144 B
  float* routeG      = (float*)(ws + 34874368);               //    524,288 B
  int* srcTok        = (int*)(ws + 35398656);                 //    280,064 B (70016 slots)
  float* srcGA       = (float*)(ws + 35678720);               //    280,064 B
  float* srcGB       = (float*)(ws + 35958784);               //    280,064 B -> ends 36,238,848

  hipLaunchKernelGGL(k_prep,      dim3(512),  dim3(256),  0, stream, w, bias, Wb, c, meta);
  hipLaunchKernelGGL(k_gating,    dim3(1024), dim3(256),  0, stream, x, wg, xb, routeE, routeG, meta);
  hipLaunchKernelGGL(k_scan,      dim3(1),    dim3(64),   0, stream, meta);
  hipLaunchKernelGGL(k_scatter,   dim3(64),   dim3(1024), 0, stream, routeE, routeG, meta,
                     srcTok, srcGA, srcGB);
  // max tiles = 65536/64 + 28 pair-pads = 1052; launch 1056
  hipLaunchKernelGGL(k_gemm_pair, dim3(1056), dim3(512),  0, stream, xb, Wb,
                     meta, srcTok, srcGA, srcGB, c, out);
}

// Round 9
// 173.056 us; speedup vs baseline: 1.0900x; 1.0900x over previous
//
#include <hip/hip_runtime.h>
#include <hip/hip_bf16.h>
#include <math.h>

#define N_TOK 65536
#define DIM   256
#define NEXP  8

using frag_ab = __attribute__((ext_vector_type(8))) short;   // 8 bf16 (4 VGPRs)
using frag_cd = __attribute__((ext_vector_type(4))) float;   // 4 fp32 acc

__device__ __forceinline__ unsigned short f2bf(float f) {
  unsigned u = __float_as_uint(f);
  u += 0x7FFFu + ((u >> 16) & 1u);   // RNE
  return (unsigned short)(u >> 16);
}

// async 16B global->LDS: lds base is wave-uniform; lane i lands at base+i*16
__device__ __forceinline__ void gl2lds16(const unsigned short* g, unsigned short* l) {
  __builtin_amdgcn_global_load_lds(
      (const __attribute__((address_space(1))) void*)g,
      (__attribute__((address_space(3))) void*)l, 16, 0, 0);
}

// meta int layout in ws: [0:64)=pair counts, [64:128)=pair base, [128:192)=cursor

// ---- k_prep: one wave per (e,o) row. Reads w ONCE: converts to bf16
// fragment-major Wb [e][k>>3][col][8] AND computes c[e][o]=bias_e.W_e[o].
__global__ __launch_bounds__(256) void k_prep(
    const float* __restrict__ w,      // expert_weight [E][OUT][D]
    const float* __restrict__ bias,   // expert_bias   [E][D]
    unsigned short* __restrict__ Wb,
    float* __restrict__ c,            // [E][OUT]
    int* __restrict__ meta) {
  int tid = threadIdx.x;
  int wid = (blockIdx.x * 256 + tid) >> 6;    // 0..2047 : one wave per (e,o)
  int lane = tid & 63;
  int e = wid >> 8, o = wid & 255;
  const float* wr = w + (size_t)(e * 256 + o) * DIM + lane * 4;
  float4 wv = *(const float4*)wr;             // row read once, coalesced
  const float* br = bias + e * DIM + lane * 4;
  float4 bv = *(const float4*)br;             // 8 KB total, L2-hot
  float s = wv.x * bv.x + wv.y * bv.y + wv.z * bv.z + wv.w * bv.w;
  #pragma unroll
  for (int m = 1; m < 64; m <<= 1) s += __shfl_xor(s, m, 64);
  if (lane == 0) c[e * 256 + o] = s;
  // fragment-major store: d = lane*4 -> elem e*65536 + (d>>3)*2048 + o*8 + (d&7)
  ushort4 h; h.x = f2bf(wv.x); h.y = f2bf(wv.y); h.z = f2bf(wv.z); h.w = f2bf(wv.w);
  *(ushort4*)(Wb + (size_t)e * 65536 + (size_t)(lane >> 1) * 2048 + o * 8 + (lane & 1) * 4) = h;
  if (blockIdx.x == 0 && tid < 192) meta[tid] = 0;
}

// ---- k_gating v2: 64 tok/block (1024 blocks -> 4 blocks/CU), 256 threads =
// 4 threads/token (dims cc === sub mod 4). Register double-buffer: chunk dc+1
// loaded to regs before computing dc (overlap). Reduce: 4-lane f64 butterfly
// (no sPar LDS, no extra barrier).
__global__ __launch_bounds__(256) void k_gating(
    const float* __restrict__ x,      // [N][D]
    const float* __restrict__ wg,     // [D][E]
    unsigned short* __restrict__ xb,  // [N][D] bf16
    int* __restrict__ routeE,         // [N] packed e1 | e2<<8
    float* __restrict__ routeG,       // [N][2]
    int* __restrict__ meta) {
  __shared__ double swg[DIM * NEXP];    // 16 KB
  __shared__ float  chunk[64 * 35];     // 8.96 KB (pad 35: bank=3*tk+cc, <=3-way)
  __shared__ int    hcnt[64];
  int tid = threadIdx.x;
  int tok0 = blockIdx.x * 64;
  int tk = tid >> 2, sub = tid & 3;     // token-local id, dim-quarter

  for (int i = tid; i < DIM * NEXP; i += 256) swg[i] = (double)wg[i];
  if (tid < 64) hcnt[tid] = 0;

  double p[NEXP];
  #pragma unroll
  for (int e = 0; e < NEXP; e++) p[e] = 0.0;

  // staging map: f in [0,512) covers [64 tok][32 dim] as float4s
  int f0 = tid, f1 = 256 + tid;
  int r0 = f0 >> 3, c40 = (f0 & 7) * 4;
  int r1 = f1 >> 3, c41 = (f1 & 7) * 4;
  const float* xs0 = x + (size_t)(tok0 + r0) * DIM + c40;
  const float* xs1 = x + (size_t)(tok0 + r1) * DIM + c41;
  unsigned short* xd0 = xb + (size_t)(tok0 + r0) * DIM + c40;
  unsigned short* xd1 = xb + (size_t)(tok0 + r1) * DIM + c41;

  float4 v0 = *(const float4*)(xs0);    // chunk 0 pre-loaded
  float4 v1 = *(const float4*)(xs1);

  for (int dc = 0; dc < 8; dc++) {      // 8 chunks of 32 dims
    __syncthreads();                    // prev compute done -> chunk reusable
    // store staged regs: LDS chunk + bf16 global
    {
      ushort4 h0; h0.x = f2bf(v0.x); h0.y = f2bf(v0.y); h0.z = f2bf(v0.z); h0.w = f2bf(v0.w);
      ushort4 h1; h1.x = f2bf(v1.x); h1.y = f2bf(v1.y); h1.z = f2bf(v1.z); h1.w = f2bf(v1.w);
      *(ushort4*)(xd0 + dc * 32) = h0;
      *(ushort4*)(xd1 + dc * 32) = h1;
      float* d0 = &chunk[r0 * 35 + c40];
      d0[0] = v0.x; d0[1] = v0.y; d0[2] = v0.z; d0[3] = v0.w;
      float* d1 = &chunk[r1 * 35 + c41];
      d1[0] = v1.x; d1[1] = v1.y; d1[2] = v1.z; d1[3] = v1.w;
    }
    // issue next chunk's loads BEFORE compute (overlap with this compute)
    float4 n0 = make_float4(0.f, 0.f, 0.f, 0.f);
    float4 n1 = make_float4(0.f, 0.f, 0.f, 0.f);
    if (dc < 7) {
      n0 = *(const float4*)(xs0 + (dc + 1) * 32);
      n1 = *(const float4*)(xs1 + (dc + 1) * 32);
    }
    __syncthreads();                    // chunk visible
    #pragma unroll
    for (int c8 = 0; c8 < 8; c8++) {    // this thread's 8 dims of the chunk
      int cc = c8 * 4 + sub;
      double xv = (double)chunk[tk * 35 + cc];
      const double* wrow = &swg[(dc * 32 + cc) * NEXP];  // 4 addrs, broadcast
      #pragma unroll
      for (int e = 0; e < NEXP; e++) p[e] += xv * wrow[e];
    }
    v0 = n0; v1 = n1;
  }

  // 4-lane butterfly reduce over the dim quarters (deterministic order)
  #pragma unroll
  for (int e = 0; e < NEXP; e++) {
    p[e] += __shfl_xor(p[e], 1, 64);
    p[e] += __shfl_xor(p[e], 2, 64);
  }

  if (sub == 0) {
    // top-2 (ties -> lowest index, matches jax.lax.top_k)
    int i1 = 0; double v1d = p[0];
    #pragma unroll
    for (int e = 1; e < NEXP; e++) { if (p[e] > v1d) { v1d = p[e]; i1 = e; } }
    int i2 = -1; double v2d = -1e300;
    #pragma unroll
    for (int e = 0; e < NEXP; e++) { if (e != i1 && p[e] > v2d) { v2d = p[e]; i2 = e; } }
    double t = exp(v2d - v1d);
    float g1 = (float)(1.0 / (1.0 + t));
    float g2 = 1.0f - g1;

    int n = tok0 + tk;
    routeE[n] = i1 | (i2 << 8);
    *(float2*)(routeG + 2 * (size_t)n) = make_float2(g1, g2);
    int a = i1 < i2 ? i1 : i2, b = i1 < i2 ? i2 : i1;
    atomicAdd(&hcnt[a * 8 + b], 1);
  }
  __syncthreads();
  if (tid < 64) atomicAdd(&meta[tid], hcnt[tid]);
}

// ---- k_scan: 64-aligned exclusive scan over 64 pair counts -----------------
__global__ void k_scan(int* __restrict__ meta) {
  if (threadIdx.x == 0) {
    int run = 0;
    for (int p = 0; p < 64; p++) {
      meta[64 + p] = run; meta[128 + p] = run;         // base, cursor
      run += ((meta[p] + 63) >> 6) << 6;
    }
  }
}

// ---- k_scatter: pair-grouped permutation; both gates per token --------------
__global__ __launch_bounds__(1024) void k_scatter(
    const int* __restrict__ routeE, const float* __restrict__ routeG,
    int* __restrict__ meta,
    int* __restrict__ srcTok, float* __restrict__ srcGA, float* __restrict__ srcGB) {
  __shared__ int cnt[64], bse[64];
  int tid = threadIdx.x;
  if (tid < 64) cnt[tid] = 0;
  __syncthreads();
  int n = blockIdx.x * 1024 + tid;
  int ep = routeE[n];
  int e1 = ep & 255, e2 = ep >> 8;
  float2 g = *(const float2*)(routeG + 2 * (size_t)n);
  int a = e1 < e2 ? e1 : e2, b = e1 < e2 ? e2 : e1;
  float ga = e1 < e2 ? g.x : g.y;      // gate of expert a (=min)
  float gb = e1 < e2 ? g.y : g.x;      // gate of expert b (=max)
  int pid = a * 8 + b;
  int r = atomicAdd(&cnt[pid], 1);
  __syncthreads();
  if (tid < 64) bse[tid] = atomicAdd(&meta[128 + tid], cnt[tid]);
  __syncthreads();
  int p = bse[pid] + r;
  srcTok[p] = n; srcGA[p] = ga; srcGB[p] = gb;
}

// ---- k_gemm_pair: pair-grouped fused GEMM. BM=64 tok, BN=256 (full OUT),
// 512 thr / 8 waves (2m x 4n), per-wave 32x64, acc[2][4].
// 16 clusters (8 per expert); B-frags stream from L2 (fragment-major) through
// a 3-deep static named register rotation bvA/bvB/bvC. Round-8 PMC showed the
// scheduler SINKS the prefetch loads to their uses (VGPR squeezed to 64,
// pipeline collapsed, MfmaUtil 10%). Fix: T19 sched_group_barrier pins the
// per-cluster emission pattern {4 VMEM_READ (prefetch C+3), 2 DS_READ (av),
// 8 MFMA} -> 3-cluster prefetch distance survives codegen; post-RA waitcnt
// pass derives counted vmcnt automatically. Gate-ratio rescale operands are
// hoisted to registers pre-loop so no stray ds_reads pollute the SGB groups.
// A-tile (64x256, 32 KB) staged once via gl2lds with proven XOR swizzle;
// zero barriers after the single staging drain.
// out written ONCE: v = sGB*acc - (sGA*cA[col] + sGB*cB[col]).
__global__ __launch_bounds__(512, 4) void k_gemm_pair(
    const unsigned short* __restrict__ xb,
    const unsigned short* __restrict__ Wb,   // fragment-major, see k_prep
    const int* __restrict__ meta,            // counts@0, base@64
    const int* __restrict__ srcTok,
    const float* __restrict__ srcGA, const float* __restrict__ srcGB,
    const float* __restrict__ c,
    float* __restrict__ out) {
  __shared__ unsigned short sA[4][64 * 64];    // 32 KB: all 4 K-subtiles
  __shared__ int   sTok[64];
  __shared__ float sGAs[64], sGBs[64];
  __shared__ float sCorA[256], sCorB[256];
  int tid = threadIdx.x;

  // map block -> (pair, m-tile)
  int rem = blockIdx.x, pid = 0, ne = 0;
  for (pid = 0; pid < 64; pid++) {
    ne = meta[pid];
    int tiles = (ne + 63) >> 6;
    if (rem < tiles) break;
    rem -= tiles;
  }
  if (pid == 64) return;
  int ea = pid >> 3, eb = pid & 7;
  int mt = rem;
  int slot0 = meta[64 + pid] + mt * 64;

  if (tid < 64) {
    int idx = mt * 64 + tid;
    bool v = idx < ne;
    sTok[tid]  = v ? srcTok[slot0 + tid] : 0;
    sGAs[tid]  = v ? srcGA[slot0 + tid] : 0.f;
    sGBs[tid]  = v ? srcGB[slot0 + tid] : 1.f;   // pad: ratio 0, never stored
  } else if (tid >= 128 && tid < 192) {
    ((float4*)sCorA)[tid - 128] = ((const float4*)(c + ea * 256))[tid - 128];
  } else if (tid >= 192 && tid < 256) {
    ((float4*)sCorB)[tid - 192] = ((const float4*)(c + eb * 256))[tid - 192];
  }
  __syncthreads();                       // sTok ready for staging addresses

  int w = tid >> 6, lane = tid & 63;
  int lrow = lane >> 3, lchk = lane & 7;

  // A staging: wave w -> rows [w*8, w*8+8), one 8-row group, 4 subtiles
  {
    int r = w * 8 + lrow;
    int cc = (lchk - r) & 7;             // global chunk for this lane's slot
    const unsigned short* src = xb + (size_t)sTok[r] * 256 + cc * 8;
    #pragma unroll
    for (int kk = 0; kk < 4; kk++)
      gl2lds16(src + kk * 64, &sA[kk][w * 8 * 64]);
  }

  // hoist per-thread gate data to regs (before the barrier-free cluster loop)
  int wm = w & 1, wn = w >> 1;           // 2 (m) x 4 (n) waves
  int lr = lane & 15, lk = lane >> 4;
  float rat[2][4];
  {
    __syncthreads();   // also the staging drain; sA read-only hereafter
    #pragma unroll
    for (int i = 0; i < 2; i++)
      #pragma unroll
      for (int rr = 0; rr < 4; rr++) {
        int m = wm * 32 + i * 16 + lk * 4 + rr;
        rat[i][rr] = sGAs[m] / sGBs[m];
      }
  }

  // A fragment read offsets: row ra, k-chunk kc=ks*4+lk -> slot (kc+ra)&7
  int offA[2][2];
  #pragma unroll
  for (int ks = 0; ks < 2; ks++)
    #pragma unroll
    for (int i = 0; i < 2; i++) {
      int ra = wm * 32 + i * 16 + lr;
      offA[ks][i] = ra * 64 + ((ks * 4 + lk + ra) & 7) * 8;
    }

  // B fragment bases (fragment-major): elem(e,col,k) at e*65536+(k>>3)*2048+col*8+(k&7)
  const unsigned short* bBaseA =
      Wb + (size_t)ea * 65536 + (size_t)lk * 2048 + (wn * 64 + lr) * 8;
  const unsigned short* bBaseB =
      Wb + (size_t)eb * 65536 + (size_t)lk * 2048 + (wn * 64 + lr) * 8;

  frag_cd acc[2][4];
  #pragma unroll
  for (int i = 0; i < 2; i++)
    #pragma unroll
    for (int j = 0; j < 4; j++)
      acc[i][j] = (frag_cd){0.f, 0.f, 0.f, 0.f};

  // cluster C in [0,16): expert = C<8 ? A : B, kk=(C&7)>>1, ks=C&1.
#define BPTR(C) (((C) < 8 ? bBaseA : bBaseB) + (((C) & 7) >> 1) * 16384 + ((C) & 1) * 8192)
#define LOADB(DST, C) do {                                                  \
    _Pragma("unroll")                                                       \
    for (int j = 0; j < 4; j++) DST[j] = *(const frag_ab*)(BPTR(C) + j * 128); \
  } while (0)

  // SchedGroupMask (m137): VMEM_READ=0x20, DS_READ=0x100, MFMA=0x8
#define SGB(M, N) __builtin_amdgcn_sched_group_barrier((M), (N), 0)

  // compute cluster C from named BUF, then refill BUF with cluster C+3.
  // SGB pins the emitted pattern per cluster: prefetch loads FIRST, then the
  // 2 av ds_reads, then the 8 MFMAs -> 3-cluster prefetch distance.
#define CLUSTER(C, BUF) do {                                                \
    const int ks_ = (C) & 1, kk_ = ((C) & 7) >> 1;                          \
    frag_ab av0 = *(const frag_ab*)(&sA[kk_][0] + offA[ks_][0]);            \
    frag_ab av1 = *(const frag_ab*)(&sA[kk_][0] + offA[ks_][1]);            \
    _Pragma("unroll")                                                       \
    for (int j = 0; j < 4; j++) {                                           \
      acc[0][j] = __builtin_amdgcn_mfma_f32_16x16x32_bf16(av0, BUF[j], acc[0][j], 0, 0, 0); \
      acc[1][j] = __builtin_amdgcn_mfma_f32_16x16x32_bf16(av1, BUF[j], acc[1][j], 0, 0, 0); \
    }                                                                       \
    if ((C) + 3 < 16) { LOADB(BUF, (C) + 3); SGB(0x020, 4); }               \
    SGB(0x100, 2);                                                          \
    SGB(0x008, 8);                                                          \
  } while (0)

  frag_ab bvA[4], bvB[4], bvC[4];
  LOADB(bvA, 0); LOADB(bvB, 1); LOADB(bvC, 2);
  SGB(0x020, 12);                        // pin the 12 prologue loads first

  CLUSTER(0, bvA);  CLUSTER(1, bvB);  CLUSTER(2, bvC);
  CLUSTER(3, bvA);  CLUSTER(4, bvB);  CLUSTER(5, bvC);
  CLUSTER(6, bvA);  CLUSTER(7, bvB);

  // between experts: acc *= rat[m] (register-resident; pure VALU)
  #pragma unroll
  for (int i = 0; i < 2; i++)
    #pragma unroll
    for (int rr = 0; rr < 4; rr++)
      #pragma unroll
      for (int j = 0; j < 4; j++) acc[i][j][rr] *= rat[i][rr];

  CLUSTER(8, bvC);  CLUSTER(9, bvA);  CLUSTER(10, bvB); CLUSTER(11, bvC);
  CLUSTER(12, bvA); CLUSTER(13, bvB); CLUSTER(14, bvC); CLUSTER(15, bvA);

#undef CLUSTER
#undef SGB
#undef LOADB
#undef BPTR

  // epilogue: C/D layout col=lane&15, row=(lane>>4)*4+reg  [m89-verified]
  // v = sGB*acc - (sGA*cA[col] + sGB*cB[col]); single write, no RMW.
  #pragma unroll
  for (int i = 0; i < 2; i++) {
    #pragma unroll
    for (int rr = 0; rr < 4; rr++) {
      int m = wm * 32 + i * 16 + lk * 4 + rr;
      if (mt * 64 + m < ne) {              // pad rows: no store
        int tokn = sTok[m];
        float sa = sGAs[m], sb = sGBs[m];
        float* orow = out + (size_t)tokn * 256;
        #pragma unroll
        for (int j = 0; j < 4; j++) {
          int col = wn * 64 + j * 16 + lr;
          orow[col] = sb * acc[i][j][rr] - (sa * sCorA[col] + sb * sCorB[col]);
        }
      }
    }
  }
}

extern "C" void kernel_launch(void* const* d_in, const int* in_sizes, int n_in,
                              void* d_out, int out_size, void* d_ws, size_t ws_size,
                              hipStream_t stream) {
  const float* x    = (const float*)d_in[0];  // [N][D]
  const float* wg   = (const float*)d_in[1];  // [D][E]
  const float* bias = (const float*)d_in[2];  // [E][D]
  const float* w    = (const float*)d_in[3];  // [E][OUT][D]
  float* out = (float*)d_out;
  char* ws = (char*)d_ws;

  // total ws usage: ~36.2 MB (proven >=39.6 MB available)
  unsigned short* xb = (unsigned short*)(ws);                 // 33,554,432 B
  unsigned short* Wb = (unsigned short*)(ws + 33554432);      //  1,048,576 B
  float* c           = (float*)(ws + 34603008);               //      8,192 B
  int* meta          = (int*)(ws + 34611200);                 //      1,024 B (192 ints used)
  int* routeE        = (int*)(ws + 34612224);                 //    262,144 B
  float* routeG      = (float*)(ws + 34874368);               //    524,288 B
  int* srcTok        = (int*)(ws + 35398656);                 //    280,064 B (70016 slots)
  float* srcGA       = (float*)(ws + 35678720);               //    280,064 B
  float* srcGB       = (float*)(ws + 35958784);               //    280,064 B -> ends 36,238,848

  hipLaunchKernelGGL(k_prep,      dim3(512),  dim3(256),  0, stream, w, bias, Wb, c, meta);
  hipLaunchKernelGGL(k_gating,    dim3(1024), dim3(256),  0, stream, x, wg, xb, routeE, routeG, meta);
  hipLaunchKernelGGL(k_scan,      dim3(1),    dim3(64),   0, stream, meta);
  hipLaunchKernelGGL(k_scatter,   dim3(64),   dim3(1024), 0, stream, routeE, routeG, meta,
                     srcTok, srcGA, srcGB);
  // max tiles = 65536/64 + 28 pair-pads = 1052; launch 1056
  hipLaunchKernelGGL(k_gemm_pair, dim3(1056), dim3(512),  0, stream, xb, Wb,
                     meta, srcTok, srcGA, srcGB, c, out);
}